// Round 2
// baseline (224.447 us; speedup 1.0000x reference)
//
#include <hip/hip_runtime.h>
#include <stdint.h>

#define D_DIM 784
#define H_DIM 1024
#define B_DIM 256
#define NBIN  10
#define G_CH  16            // chunk length (i's per main block)
#define T_CH  49            // D_DIM / G_CH
#define BT    16            // batch tile per main block
#define LOG2E 1.4426950408889634f

typedef _Float16 half8_t  __attribute__((ext_vector_type(8)));
typedef __fp16   fp16x2_t __attribute__((ext_vector_type(2)));
typedef float    float4_t __attribute__((ext_vector_type(4)));

// ---------- prep: Wt2[j][h] = W[h][j] * log2(e) ----------
__global__ void k_transpose(const float* __restrict__ W, float* __restrict__ Wt2) {
    int j = blockIdx.x;          // 0..783
    int t = threadIdx.x;         // 0..255
    int h = t * 4;
    float4 v;
    v.x = W[(size_t)(h+0)*D_DIM + j] * LOG2E;
    v.y = W[(size_t)(h+1)*D_DIM + j] * LOG2E;
    v.z = W[(size_t)(h+2)*D_DIM + j] * LOG2E;
    v.w = W[(size_t)(h+3)*D_DIM + j] * LOG2E;
    ((float4*)(Wt2 + (size_t)j*H_DIM))[t] = v;
}

// ---------- prep: V -> f16 MFMA B-fragment layout ----------
// VB[i][kk][lane][jj]: lane needs B[k = kk*32 + (lane>>4)*8 + jj][n = lane&15]
__global__ void k_vbprep(const float* __restrict__ V, _Float16* __restrict__ VB) {
    int i  = blockIdx.x;         // 0..783
    int kk = blockIdx.y;         // 0..31
    int t  = threadIdx.x;        // 0..127
    int l  = t >> 1;
    int j0 = (t & 1) * 4;
    int n  = l & 15;
    int hbase = kk*32 + (l>>4)*8 + j0;
    union { _Float16 h[4]; uint2 u; } o;
    #pragma unroll
    for (int jj = 0; jj < 4; ++jj) {
        float v = (n < NBIN) ? V[((size_t)i*H_DIM + hbase + jj)*NBIN + n] : 0.0f;
        o.h[jj] = (_Float16)v;
    }
    size_t idx = ((size_t)(i*32 + kk)*64 + l)*8 + j0;
    *((uint2*)(VB + idx)) = o.u;
}

// ---------- partial sums per chunk: P[t][b][h] ----------
template<typename CT>
__global__ void k_partial(const float* __restrict__ Wt2, const int* __restrict__ x,
                          CT* __restrict__ PA) {
    int tc   = blockIdx.x;       // 0..48
    int hblk = blockIdx.y;       // 0..3
    int bblk = blockIdx.z;       // 0..3
    int t    = threadIdx.x;      // 0..255
    int h    = hblk*256 + t;

    __shared__ __align__(16) float xs[64][G_CH];
    {
        int bl = t >> 2, q = t & 3;
        int4 xi = *((const int4*)(x + (size_t)(bblk*64 + bl)*D_DIM + tc*G_CH + q*4));
        float4 xf = make_float4((float)xi.x, (float)xi.y, (float)xi.z, (float)xi.w);
        *((float4*)&xs[bl][q*4]) = xf;
    }
    float w[G_CH];
    #pragma unroll
    for (int j = 0; j < G_CH; ++j) w[j] = Wt2[(size_t)(tc*G_CH + j)*H_DIM + h];
    __syncthreads();

    for (int bl = 0; bl < 64; ++bl) {
        float acc = 0.0f;
        #pragma unroll
        for (int q = 0; q < 4; ++q) {
            float4 xf = *((float4*)&xs[bl][q*4]);
            acc += xf.x*w[q*4+0] + xf.y*w[q*4+1] + xf.z*w[q*4+2] + xf.w*w[q*4+3];
        }
        PA[((size_t)tc*B_DIM + bblk*64 + bl)*H_DIM + h] = (CT)acc;
    }
}

// ---------- exclusive scan over chunks (in place): PA[t] := c*log2e + sum_{t'<t} P[t'] ----------
template<typename CT>
__global__ void k_scan(const float* __restrict__ c, CT* __restrict__ PA) {
    int b = blockIdx.x >> 2;
    int h = (blockIdx.x & 3)*256 + threadIdx.x;
    float acc = c[h] * LOG2E;
    size_t stride = (size_t)B_DIM * H_DIM;
    size_t idx = (size_t)b*H_DIM + h;
    for (int tt = 0; tt < T_CH; ++tt) {
        float v = (float)PA[idx];
        PA[idx] = (CT)acc;
        acc += v;
        idx += stride;
    }
}

// ---------- main fused kernel ----------
template<typename CT>
__global__ __launch_bounds__(256, 3)
void k_main(const float* __restrict__ Wt2, const _Float16* __restrict__ VB,
            const CT* __restrict__ PA, const int* __restrict__ x,
            const float* __restrict__ bias, float* __restrict__ out) {
    int tc  = blockIdx.x;        // chunk 0..48
    int bt  = blockIdx.y;        // batch tile 0..15
    int tid = threadIdx.x;
    int w   = tid >> 6;          // wave 0..3 (K-split)
    int l   = tid & 63;
    int bl  = l & 15;            // batch row within tile == MFMA A row == C col(n) role
    int kg  = l >> 4;            // 0..3
    int bg  = bt*BT + bl;        // global batch row this lane's A-frag belongs to
    int i0  = tc*G_CH;

    __shared__ float red[4][256][5];                 // stride-5 pad: conflict-free
    __shared__ float bs[G_CH][16];
    __shared__ __align__(16) float plds[BT][NBIN][20];

    {   // stage bias chunk
        int ii = tid >> 4, n = tid & 15;
        bs[ii][n] = (n < NBIN) ? bias[(size_t)(i0+ii)*NBIN + n] : 0.0f;
    }

    // load checkpoint a-state (already scaled by log2e): thread owns
    // h = w*256 + kg*8 + m*32 + j  (== MFMA A-fragment ownership)
    float a[8][8];
    {
        const CT* src = PA + ((size_t)tc*B_DIM + bg)*H_DIM + w*256 + kg*8;
        #pragma unroll
        for (int m = 0; m < 8; ++m)
            #pragma unroll
            for (int j = 0; j < 8; ++j)
                a[m][j] = (float)src[m*32 + j];
    }
    __syncthreads();

    const float4* wt4 = (const float4*)Wt2;
    for (int ii = 0; ii < G_CH; ++ii) {
        int i = i0 + ii;
        float xvf = (float)x[(size_t)bg*D_DIM + i];

        // prefetch B-fragments for this wave's 8 k-steps
        uint4 vb[8];
        const uint4* vbp = (const uint4*)VB + ((size_t)i*32 + w*8)*64 + l;
        #pragma unroll
        for (int m = 0; m < 8; ++m) vb[m] = vbp[m*64];

        float4_t cfrag = {0.f, 0.f, 0.f, 0.f};
        #pragma unroll
        for (int m = 0; m < 8; ++m) {
            // sigmoid of CURRENT a (pre-update, matches reference order) -> f16 A-frag
            union { half8_t h8; uint u32[4]; } af;
            #pragma unroll
            for (int p = 0; p < 4; ++p) {
                float s0 = __builtin_amdgcn_rcpf(1.0f + __builtin_amdgcn_exp2f(-a[m][2*p]));
                float s1 = __builtin_amdgcn_rcpf(1.0f + __builtin_amdgcn_exp2f(-a[m][2*p+1]));
                union { fp16x2_t v; uint u; } cv;
                cv.v = __builtin_amdgcn_cvt_pkrtz(s0, s1);
                af.u32[p] = cv.u;
            }
            union { half8_t h8; uint4 u; } bf;
            bf.u = vb[m];
            cfrag = __builtin_amdgcn_mfma_f32_16x16x32_f16(af.h8, bf.h8, cfrag, 0, 0, 0);

            // rank-1 update for next i
            int hb = (w*256 + kg*8 + m*32) >> 2;
            float4 w0 = wt4[(size_t)i*(H_DIM/4) + hb];
            float4 w1 = wt4[(size_t)i*(H_DIM/4) + hb + 1];
            a[m][0] += xvf*w0.x; a[m][1] += xvf*w0.y; a[m][2] += xvf*w0.z; a[m][3] += xvf*w0.w;
            a[m][4] += xvf*w1.x; a[m][5] += xvf*w1.y; a[m][6] += xvf*w1.z; a[m][7] += xvf*w1.w;
        }

        // cross-wave K reduction of C
        red[w][l][0] = cfrag[0]; red[w][l][1] = cfrag[1];
        red[w][l][2] = cfrag[2]; red[w][l][3] = cfrag[3];
        __syncthreads();
        // this thread finalizes C row r = w for its lane: row = kg*4 + w, col n = bl
        float tot = red[0][l][w] + red[1][l][w] + red[2][l][w] + red[3][l][w];
        int n = bl;
        float v = (n < NBIN) ? tot + bs[ii][n] : -3.0e38f;
        float vm = v;
        vm = fmaxf(vm, __shfl_xor(vm, 1));
        vm = fmaxf(vm, __shfl_xor(vm, 2));
        vm = fmaxf(vm, __shfl_xor(vm, 4));
        vm = fmaxf(vm, __shfl_xor(vm, 8));
        float e = __builtin_amdgcn_exp2f((v - vm) * LOG2E);
        float ss = e;
        ss += __shfl_xor(ss, 1);
        ss += __shfl_xor(ss, 2);
        ss += __shfl_xor(ss, 4);
        ss += __shfl_xor(ss, 8);
        float p = e * __builtin_amdgcn_rcpf(ss);
        if (n < NBIN) plds[kg*4 + w][n][ii] = p;
        __syncthreads();   // protects red (next iter) and plds (final readback)
    }

    // coalesced chunk writeback: out[b][n][i0..i0+15]
    if (tid < BT*NBIN) {
        int bb = tid / NBIN, n = tid % NBIN;
        size_t base = ((size_t)(bt*BT + bb)*NBIN + n)*D_DIM + i0;
        #pragma unroll
        for (int q = 0; q < 4; ++q) {
            float4 v = *((float4*)&plds[bb][n][q*4]);
            *((float4*)(out + base + q*4)) = v;
        }
    }
}

extern "C" void kernel_launch(void* const* d_in, const int* in_sizes, int n_in,
                              void* d_out, int out_size, void* d_ws, size_t ws_size,
                              hipStream_t stream) {
    const int*   x    = (const int*)d_in[0];
    const float* W    = (const float*)d_in[1];
    const float* c    = (const float*)d_in[2];
    const float* V    = (const float*)d_in[3];
    const float* bias = (const float*)d_in[4];
    float* out = (float*)d_out;

    char* ws = (char*)d_ws;
    size_t off = 0;
    float* Wt2 = (float*)(ws + off);
    off += (size_t)D_DIM * H_DIM * sizeof(float);
    off = (off + 255) & ~(size_t)255;
    _Float16* VB = (_Float16*)(ws + off);
    off += (size_t)D_DIM * 32 * 64 * 8 * sizeof(_Float16);
    off = (off + 255) & ~(size_t)255;
    size_t pa_f32 = (size_t)T_CH * B_DIM * H_DIM * sizeof(float);
    bool f32ck = (off + pa_f32) <= ws_size;

    k_transpose<<<dim3(D_DIM), 256, 0, stream>>>(W, Wt2);
    k_vbprep<<<dim3(D_DIM, 32), 128, 0, stream>>>(V, VB);

    if (f32ck) {
        float* PA = (float*)(ws + off);
        k_partial<float><<<dim3(T_CH, 4, 4), 256, 0, stream>>>(Wt2, x, PA);
        k_scan<float><<<dim3(B_DIM * 4), 256, 0, stream>>>(c, PA);
        k_main<float><<<dim3(T_CH, B_DIM / BT), 256, 0, stream>>>(Wt2, VB, PA, x, bias, out);
    } else {
        _Float16* PA = (_Float16*)(ws + off);
        k_partial<_Float16><<<dim3(T_CH, 4, 4), 256, 0, stream>>>(Wt2, x, PA);
        k_scan<_Float16><<<dim3(B_DIM * 4), 256, 0, stream>>>(c, PA);
        k_main<_Float16><<<dim3(T_CH, B_DIM / BT), 256, 0, stream>>>(Wt2, VB, PA, x, bias, out);
    }
}